// Round 5
// baseline (338.788 us; speedup 1.0000x reference)
//
#include <hip/hip_runtime.h>
#include <hip/hip_bf16.h>
#include <math.h>

#define QN 128
#define SN 128
#define HN 32
#define CN (QN * SN)
#define TILE_R 64
#define NTILE 4
#define BBLK (TILE_R * NTILE)  // 256 batch rows per block

typedef unsigned int u32;

// Direct global->LDS, 16B per lane. LDS dest = wave-uniform base + lane*16B.
__device__ __forceinline__ void gload16(const float* g, float* l) {
  __builtin_amdgcn_global_load_lds(
      (const __attribute__((address_space(1))) u32*)(const void*)g,
      (__attribute__((address_space(3))) u32*)(void*)l,
      16, 0, 0);
}

// Block: 256 threads (4 waves), one q, 256 batch rows in 4 tiles of 64.
// Compute: lane = row, wave w owns h-octet h0=w*8 -> W1/b1/W2 wave-uniform
// (SGPR broadcast). LDS layout (proven 0-conflict in rounds 2/4):
//   xtile[r*128 + ((c4 ^ (r&31))*4 + c&3)]   (512B row stride, quad XOR)
// Staged via global_load_lds with LINEAR LDS dest and the INVERSE swizzle
// applied to the per-lane GLOBAL source column (rule 21: both-sides swizzle,
// LDS stays linear). Each instr covers 2 full contiguous 512B row segments
// (permuted within-row order -> coalescer merges; zero over-fetch).
// Double-buffered tiles: STAGE(t+1) issues before compute(t); the single
// barrier per tile drains vmcnt AFTER compute -> staging latency hidden.
__global__ __launch_bounds__(256, 2)
void divenc_kernel(const float* __restrict__ x,
                   const float* __restrict__ W1,
                   const float* __restrict__ b1,
                   const float* __restrict__ W2,
                   const float* __restrict__ b2,
                   float* __restrict__ out) {
  const int q    = blockIdx.x;
  const int b0   = blockIdx.y * BBLK;
  const int tid  = threadIdx.x;
  const int lane = tid & 63;
  const int wid  = __builtin_amdgcn_readfirstlane(tid >> 6);
  const int h0   = wid * 8;  // uniform per wave

  __shared__ float xs[2][TILE_R * SN];  // two 32 KB tile buffers
  __shared__ float parts[2][4][TILE_R];

  const float* __restrict__ w1q = W1 + (size_t)q * (SN * HN);

  float b1v[8], w2v[8];
  #pragma unroll
  for (int j = 0; j < 8; ++j) {
    b1v[j] = b1[q * HN + h0 + j];   // uniform -> s_load
    w2v[j] = W2[q * HN + h0 + j];
  }
  const float b2q = b2[q];

  const float* xbase = x + (size_t)b0 * CN + (size_t)q * SN;

  // Stage tile t into xs[t&1]: wave w covers rows w*16..w*16+15,
  // 8 instrs of 1KB (2 rows) each. Source col carries the inverse swizzle.
  auto STAGE = [&](int t) {
    float* buf = xs[t & 1];
    const float* tb = xbase + (size_t)t * TILE_R * CN;
    #pragma unroll
    for (int k = 0; k < 8; ++k) {
      const int r0 = wid * 16 + k * 2;          // wave-uniform
      const int r  = r0 + (lane >> 5);          // per-lane row
      const int c  = ((lane & 31) ^ (r & 31)) << 2;  // inverse-swizzled col
      gload16(tb + (size_t)r * CN + c, buf + r0 * SN);
    }
  };

  STAGE(0);
  __syncthreads();  // drains vmcnt(0): tile 0 resident

  #pragma unroll 1
  for (int t = 0; t < NTILE; ++t) {
    if (t + 1 < NTILE) STAGE(t + 1);  // async, into other buffer, no regs

    const float* xrow = xs[t & 1] + (lane << 7);
    float acc[8];
    #pragma unroll
    for (int j = 0; j < 8; ++j) acc[j] = 0.f;

    #pragma unroll
    for (int s4 = 0; s4 < SN; s4 += 4) {
      const float4 xv = *reinterpret_cast<const float4*>(
          xrow + (((s4 >> 2) ^ (lane & 31)) << 2));
      #pragma unroll
      for (int u = 0; u < 4; ++u) {
        const float xu = (&xv.x)[u];
        const float* __restrict__ wrow = w1q + (s4 + u) * HN + h0;  // uniform
        #pragma unroll
        for (int j = 0; j < 8; ++j)
          acc[j] = fmaf(xu, wrow[j], acc[j]);
      }
    }

    // epilogue: +b1, ELU, dot W2 over this wave's 8 h
    float part = 0.f;
    #pragma unroll
    for (int j = 0; j < 8; ++j) {
      float v = acc[j] + b1v[j];
      v = v > 0.f ? v : expm1f(v);
      part = fmaf(v, w2v[j], part);
    }
    parts[t & 1][wid][lane] = part;

    __syncthreads();  // tile t reads done; parts visible; tile t+1 resident

    if (wid == 0) {
      const float o = parts[t & 1][0][lane] + parts[t & 1][1][lane] +
                      parts[t & 1][2][lane] + parts[t & 1][3][lane] + b2q;
      out[(size_t)(b0 + t * TILE_R + lane) * QN + q] = o;
    }
  }
}

extern "C" void kernel_launch(void* const* d_in, const int* in_sizes, int n_in,
                              void* d_out, int out_size, void* d_ws, size_t ws_size,
                              hipStream_t stream) {
  const float* x  = (const float*)d_in[0];
  const float* W1 = (const float*)d_in[1];
  const float* b1 = (const float*)d_in[2];
  const float* W2 = (const float*)d_in[3];
  const float* b2 = (const float*)d_in[4];
  float* out = (float*)d_out;

  const int B = in_sizes[0] / CN;  // 2048
  dim3 grid(QN, B / BBLK);
  divenc_kernel<<<grid, 256, 0, stream>>>(x, W1, b1, W2, b2, out);
}

// Round 6
// 61.168 us; speedup vs baseline: 5.5386x; 5.5386x over previous
//
#include <hip/hip_runtime.h>
#include <hip/hip_bf16.h>
#include <math.h>

#define QN 128
#define SN 128
#define HN 32
#define CN (QN * SN)
#define TILE_R 64   // batch rows per block (one tile, no loop)

// Block: 256 threads (4 waves), one q, 64 batch rows. One tile per block ->
// 4096 small independent blocks; resident blocks destagger so staging latency
// hides under other blocks' compute (round-4's lockstep phases were the stall).
// Compute: lane = row, wave w owns h-octet h0=w*8 -> W1/b1/W2 operands are
// wave-uniform (SGPR broadcast). x staged coalesced into XOR-swizzled LDS
// (layout proven 0-conflict in rounds 2/4). No global_load_lds (R3/R5: the
// compiler waterfalls the intrinsic here -> 4-6x regression).
__global__ __launch_bounds__(256, 4)
void divenc_kernel(const float* __restrict__ x,
                   const float* __restrict__ W1,
                   const float* __restrict__ b1,
                   const float* __restrict__ W2,
                   const float* __restrict__ b2,
                   float* __restrict__ out) {
  const int q    = blockIdx.x;
  const int b0   = blockIdx.y * TILE_R;
  const int tid  = threadIdx.x;
  const int lane = tid & 63;
  const int wid  = __builtin_amdgcn_readfirstlane(tid >> 6);
  const int h0   = wid * 8;  // uniform per wave

  __shared__ float xtile[TILE_R * SN];  // 32 KB, XOR-swizzled rows
  __shared__ float parts[4][TILE_R];

  const float* __restrict__ w1q = W1 + (size_t)q * (SN * HN);

  float b1v[8], w2v[8];
  #pragma unroll
  for (int j = 0; j < 8; ++j) {
    b1v[j] = b1[q * HN + h0 + j];   // uniform -> s_load
    w2v[j] = W2[q * HN + h0 + j];
  }
  const float b2q = b2[q];

  // ---- stage: coalesced (each instr = 8 contiguous 512B row segments),
  // written immediately to swizzled LDS (no long-lived registers).
  const float* tb = x + (size_t)b0 * CN + (size_t)q * SN;
  #pragma unroll
  for (int i = 0; i < 8; ++i) {
    const int f = i * 256 + tid;
    const int r = f >> 5, c = f & 31;
    const float4 vv = *reinterpret_cast<const float4*>(tb + (size_t)r * CN + c * 4);
    *reinterpret_cast<float4*>(&xtile[r * SN + ((c ^ (r & 31)) << 2)]) = vv;
  }
  __syncthreads();

  // ---- compute: lane's row from LDS, W1 broadcast from SGPRs
  float acc[8];
  #pragma unroll
  for (int j = 0; j < 8; ++j) acc[j] = 0.f;

  #pragma unroll 4
  for (int s4 = 0; s4 < SN; s4 += 4) {
    const float4 xv = *reinterpret_cast<const float4*>(
        &xtile[(lane << 7) + (((s4 >> 2) ^ (lane & 31)) << 2)]);
    #pragma unroll
    for (int u = 0; u < 4; ++u) {
      const float xu = (&xv.x)[u];
      const float* __restrict__ wrow = w1q + (s4 + u) * HN + h0;  // uniform
      #pragma unroll
      for (int j = 0; j < 8; ++j)
        acc[j] = fmaf(xu, wrow[j], acc[j]);
    }
  }

  // ---- epilogue: +b1, ELU, dot W2 over this wave's 8 h
  float part = 0.f;
  #pragma unroll
  for (int j = 0; j < 8; ++j) {
    float v = acc[j] + b1v[j];
    v = v > 0.f ? v : expm1f(v);
    part = fmaf(v, w2v[j], part);
  }
  parts[wid][lane] = part;
  __syncthreads();

  if (wid == 0) {
    const float o = parts[0][lane] + parts[1][lane] + parts[2][lane] +
                    parts[3][lane] + b2q;
    out[(size_t)(b0 + lane) * QN + q] = o;
  }
}

extern "C" void kernel_launch(void* const* d_in, const int* in_sizes, int n_in,
                              void* d_out, int out_size, void* d_ws, size_t ws_size,
                              hipStream_t stream) {
  const float* x  = (const float*)d_in[0];
  const float* W1 = (const float*)d_in[1];
  const float* b1 = (const float*)d_in[2];
  const float* W2 = (const float*)d_in[3];
  const float* b2 = (const float*)d_in[4];
  float* out = (float*)d_out;

  const int B = in_sizes[0] / CN;  // 2048
  dim3 grid(QN, B / TILE_R);
  divenc_kernel<<<grid, 256, 0, stream>>>(x, W1, b1, W2, b2, out);
}